// Round 3
// baseline (3968.917 us; speedup 1.0000x reference)
//
#include <hip/hip_runtime.h>
#include <hip/hip_bf16.h>
#include <math.h>

#define CDIM 192
#define NHEADS 8
#define HD 24
#define NTOK 131072   /* B*H*W = 2*256*256 */

typedef __attribute__((ext_vector_type(4))) float floatx4;
typedef __attribute__((ext_vector_type(8))) short bf16x8;

static __device__ __forceinline__ float bf2f(__hip_bfloat16 h) { return __bfloat162float(h); }
static __device__ __forceinline__ __hip_bfloat16 f2bf(float f) { return __float2bfloat16(f); }
static __device__ __forceinline__ float s2f(short s) {
  union { unsigned u; float f; } c; c.u = ((unsigned)(unsigned short)s) << 16; return c.f;
}
static __device__ __forceinline__ short f2s(float f) {
  __hip_bfloat16 h = __float2bfloat16(f);
  union { __hip_bfloat16 h; short s; } c; c.h = h; return c.s;
}

// ---------------- KC: f32 -> bf16 convert ----------------
__global__ __launch_bounds__(256) void kcvt(
    const float* __restrict__ in, __hip_bfloat16* __restrict__ out, int n) {
  int i = blockIdx.x * 256 + threadIdx.x;
  if (i < n) out[i] = f2bf(in[i]);
}

// ---------------- K0: pad pout_w (192,510) f32 -> (192,512) bf16 ----------------
__global__ __launch_bounds__(256) void k0_pad(
    const float* __restrict__ w, __hip_bfloat16* __restrict__ o) {
  int idx = blockIdx.x * 256 + threadIdx.x;   // 192*512
  int n = idx >> 9, k = idx & 511;
  o[idx] = (k < 510) ? f2bf(w[n * 510 + k]) : f2bf(0.f);
}

// ---------------- K1: LN1 + shift + window partition (f32 in, bf16 out) ----------------
__global__ __launch_bounds__(256) void k1_ln_window(
    const float* __restrict__ x,
    const float* __restrict__ w,
    const float* __restrict__ bsh,
    __hip_bfloat16* __restrict__ out) {
  int wave = threadIdx.x >> 6, lane = threadIdx.x & 63;
  int t = blockIdx.x * 4 + wave;           // window-order token
  int wid = t >> 6, n = t & 63;
  int b = wid >> 10, wi = (wid >> 5) & 31, wj = wid & 31;
  int ti = n >> 3, tj = n & 7;
  int i = ((wi << 3) + ti + 4) & 255;      // unshifted row (roll -4)
  int j = ((wj << 3) + tj + 4) & 255;
  int pix = (i << 8) + j;
  int c0 = lane * 3;
  float v0 = x[((long)(b * CDIM + c0    ) << 16) + pix];
  float v1 = x[((long)(b * CDIM + c0 + 1) << 16) + pix];
  float v2 = x[((long)(b * CDIM + c0 + 2) << 16) + pix];
  float s = v0 + v1 + v2;
  float sq = v0 * v0 + v1 * v1 + v2 * v2;
  for (int off = 32; off; off >>= 1) { s += __shfl_xor(s, off); sq += __shfl_xor(sq, off); }
  float mean = s * (1.0f / 192.0f);
  float var  = sq * (1.0f / 192.0f) - mean * mean;
  float rstd = rsqrtf(var + 1e-5f);
  long base = (long)t * CDIM + c0;
  out[base    ] = f2bf((v0 - mean) * rstd * w[c0    ] + bsh[c0    ]);
  out[base + 1] = f2bf((v1 - mean) * rstd * w[c0 + 1] + bsh[c0 + 1]);
  out[base + 2] = f2bf((v2 - mean) * rstd * w[c0 + 2] + bsh[c0 + 2]);
}

// ---------------- generic MFMA GEMM: C(M,N) = A(M,K) * B(N,K)^T ----------------
// block = 4 waves; wave computes one 16x16 tile. EPI: 0 plain, 1 +bias(f32)
template <int EPI>
__global__ __launch_bounds__(256) void gemm_bt(
    const __hip_bfloat16* __restrict__ A,
    const __hip_bfloat16* __restrict__ B,
    const float* __restrict__ bias,
    __hip_bfloat16* __restrict__ C,
    int N, int K, int lda, int ldb, int ldc) {
  int wave = threadIdx.x >> 6, lane = threadIdx.x & 63;
  int m0 = blockIdx.y << 4;
  int n0 = (blockIdx.x * 4 + wave) << 4;
  int r16 = lane & 15, quad = lane >> 4;
  int arow = m0 + r16;
  int brow = n0 + r16; if (brow >= N) brow = N - 1;   // clamp (results discarded)
  const __hip_bfloat16* Ap = A + (long)arow * lda + quad * 8;
  const __hip_bfloat16* Bp = B + (long)brow * ldb + quad * 8;
  floatx4 acc = {0.f, 0.f, 0.f, 0.f};
  for (int k = 0; k < K; k += 32) {
    bf16x8 a  = *(const bf16x8*)(Ap + k);
    bf16x8 bb = *(const bf16x8*)(Bp + k);
    acc = __builtin_amdgcn_mfma_f32_16x16x32_bf16(a, bb, acc, 0, 0, 0);
  }
  int col = n0 + r16;
  if (col < N) {
    float badd = (EPI == 1) ? bias[col] : 0.f;
    for (int r = 0; r < 4; ++r) {
      int orow = m0 + quad * 4 + r;
      C[(long)orow * ldc + col] = f2bf(acc[r] + badd);
    }
  }
}

// ---------------- K3: window attention, one block per (head, window-in-chunk) ----------------
__global__ __launch_bounds__(64) void k3_attn(
    const __hip_bfloat16* __restrict__ qkv,   // chunk base, stride 576, 256 windows
    const float* __restrict__ rpb,
    __hip_bfloat16* __restrict__ out,         // full attnout (NTOK,192)
    int wid0) {
  __shared__ float kk[64][HD + 1];
  __shared__ float vv[64][HD + 1];
  int h = blockIdx.x, widl = blockIdx.y;
  int wid = wid0 + widl;                      // global window id
  int n = threadIdx.x;
  long tb = (long)(widl * 64 + n) * 576 + h * HD;
  for (int d = 0; d < HD; ++d) {
    kk[n][d] = bf2f(qkv[tb + 192 + d]);
    vv[n][d] = bf2f(qkv[tb + 384 + d]);
  }
  float q[HD];
  for (int d = 0; d < HD; ++d) q[d] = bf2f(qkv[tb + d]) * 0.20412414523193154f;
  __syncthreads();
  int wi = (wid >> 5) & 31, wj = wid & 31;
  int ti = n >> 3, tj = n & 7;
  int gi = wi * 8 + ti, gj = wj * 8 + tj;
  int rq = ((gi < 248) ? 0 : (gi < 252 ? 1 : 2)) * 3 + ((gj < 248) ? 0 : (gj < 252 ? 1 : 2));
  float s[64];
  float mx = -1e30f;
  for (int m = 0; m < 64; ++m) {
    float acc = 0.f;
    for (int d = 0; d < HD; ++d) acc += q[d] * kk[m][d];
    int si = m >> 3, sj = m & 7;
    int idx = (ti - si + 7) * 15 + (tj - sj + 7);
    acc += rpb[idx * NHEADS + h];
    int gsi = wi * 8 + si, gsj = wj * 8 + sj;
    int rk = ((gsi < 248) ? 0 : (gsi < 252 ? 1 : 2)) * 3 + ((gsj < 248) ? 0 : (gsj < 252 ? 1 : 2));
    if (rk != rq) acc -= 100.0f;
    s[m] = acc;
    mx = fmaxf(mx, acc);
  }
  float sum = 0.f;
  for (int m = 0; m < 64; ++m) { s[m] = expf(s[m] - mx); sum += s[m]; }
  float rs = 1.0f / sum;
  long ob = (long)(wid * 64 + n) * CDIM + h * HD;
  for (int d = 0; d < HD; ++d) {
    float acc = 0.f;
    for (int m = 0; m < 64; ++m) acc += s[m] * vv[m][d];
    out[ob + d] = f2bf(acc * rs);
  }
}

// ---------------- K4: residual + unshift scatter + LN2 stats ----------------
__global__ __launch_bounds__(256) void k4_resln(
    const float* __restrict__ x,
    const __hip_bfloat16* __restrict__ tmp,   // proj out, window order
    __hip_bfloat16* __restrict__ x2,          // unshifted token-major (NTOK,192)
    float* __restrict__ stats) {              // (NTOK,2): mean, rstd
  int wave = threadIdx.x >> 6, lane = threadIdx.x & 63;
  int t = blockIdx.x * 4 + wave;
  int wid = t >> 6, n = t & 63;
  int b = wid >> 10, wi = (wid >> 5) & 31, wj = wid & 31;
  int ti = n >> 3, tj = n & 7;
  int i = ((wi << 3) + ti + 4) & 255;
  int j = ((wj << 3) + tj + 4) & 255;
  int pix = (i << 8) + j;
  long t2 = ((long)b << 16) + pix;
  int c0 = lane * 3;
  long tb = (long)t * CDIM + c0;
  float v0 = x[((long)(b * CDIM + c0    ) << 16) + pix] + bf2f(tmp[tb    ]);
  float v1 = x[((long)(b * CDIM + c0 + 1) << 16) + pix] + bf2f(tmp[tb + 1]);
  float v2 = x[((long)(b * CDIM + c0 + 2) << 16) + pix] + bf2f(tmp[tb + 2]);
  long ob = t2 * CDIM + c0;
  x2[ob] = f2bf(v0); x2[ob + 1] = f2bf(v1); x2[ob + 2] = f2bf(v2);
  float s = v0 + v1 + v2, sq = v0 * v0 + v1 * v1 + v2 * v2;
  for (int off = 32; off; off >>= 1) { s += __shfl_xor(s, off); sq += __shfl_xor(sq, off); }
  float mean = s * (1.0f / 192.0f);
  float var  = sq * (1.0f / 192.0f) - mean * mean;
  float rstd = rsqrtf(var + 1e-5f);
  if (lane == 0) { stats[2 * t2] = mean; stats[2 * t2 + 1] = rstd; }
}

// ---------------- K6: pin GEMM with fused LN2, row-chunked (34 image rows) ----------------
__global__ __launch_bounds__(256) void gemm_pin(
    const __hip_bfloat16* __restrict__ x2,    // (NTOK,192)
    const float* __restrict__ stats,          // (NTOK,2)
    const __hip_bfloat16* __restrict__ nw,    // bf16 blob: norm2_w
    const __hip_bfloat16* __restrict__ nb,    // bf16 blob: norm2_b
    const __hip_bfloat16* __restrict__ B,     // pin_w bf16 (1020,192)
    __hip_bfloat16* __restrict__ C,           // (34*256, 1020) chunk
    int b, int r0) {
  int wave = threadIdx.x >> 6, lane = threadIdx.x & 63;
  int m0 = blockIdx.y << 4;
  int n0 = (blockIdx.x * 4 + wave) << 4;
  int r16 = lane & 15, quad = lane >> 4;
  int arow = m0 + r16;                        // [0, 8704)
  int il = arow >> 8, j = arow & 255;
  int gi = r0 - 1 + il; gi = gi < 0 ? 0 : (gi > 255 ? 255 : gi);
  long t = ((long)b << 16) + (gi << 8) + j;
  float mean = stats[2 * t], rstd = stats[2 * t + 1];
  int brow = n0 + r16; if (brow >= 1020) brow = 1019;
  const __hip_bfloat16* Ap = x2 + t * CDIM + quad * 8;
  const __hip_bfloat16* Bp = B + (long)brow * CDIM + quad * 8;
  const short* nws = (const short*)nw;
  const short* nbs = (const short*)nb;
  floatx4 acc = {0.f, 0.f, 0.f, 0.f};
  for (int k = 0; k < CDIM; k += 32) {
    bf16x8 a  = *(const bf16x8*)(Ap + k);
    bf16x8 w8 = *(const bf16x8*)(nws + quad * 8 + k);
    bf16x8 b8 = *(const bf16x8*)(nbs + quad * 8 + k);
    bf16x8 an;
    for (int e = 0; e < 8; ++e)
      an[e] = f2s((s2f(a[e]) - mean) * rstd * s2f(w8[e]) + s2f(b8[e]));
    bf16x8 bb = *(const bf16x8*)(Bp + k);
    acc = __builtin_amdgcn_mfma_f32_16x16x32_bf16(an, bb, acc, 0, 0, 0);
  }
  int col = n0 + r16;
  if (col < 1020) {
    for (int r = 0; r < 4; ++r) {
      int orow = m0 + quad * 4 + r;
      C[(long)orow * 1020 + col] = f2bf(acc[r]);
    }
  }
}

// ---------------- K7: depthwise 3x3 + gated exact GELU, chunked ----------------
__global__ __launch_bounds__(256) void k7_dwgate(
    const __hip_bfloat16* __restrict__ pin,  // (34*256, 1020) chunk (rows r0-1..r0+32 clamped)
    const float* __restrict__ wdw,           // (1020, 9) f32
    __hip_bfloat16* __restrict__ out,        // (32*256, 512) zero-padded cols 510,511
    int r0) {
  int p = blockIdx.x;                        // [0, 8192): 32 rows x 256 cols
  int il = p >> 8, j = p & 255;
  int gi = r0 + il;
  for (int it = 0; it < 2; ++it) {
    int hc = threadIdx.x + it * 256;
    long ob = (long)p * 512 + hc;
    if (hc >= 510) { out[ob] = f2bf(0.f); continue; }
    float a = 0.f, g = 0.f;
    for (int di = -1; di <= 1; ++di) {
      int ii = gi + di; if (ii < 0 || ii > 255) continue;
      int br = il + di + 1;                  // [0, 33]
      for (int dj = -1; dj <= 1; ++dj) {
        int jj = j + dj; if (jj < 0 || jj > 255) continue;
        long nbase = ((long)((br << 8) + jj)) * 1020;
        int widx = (di + 1) * 3 + (dj + 1);
        a += wdw[hc * 9 + widx]         * bf2f(pin[nbase + hc]);
        g += wdw[(hc + 510) * 9 + widx] * bf2f(pin[nbase + hc + 510]);
      }
    }
    float ge = 0.5f * a * (1.0f + erff(a * 0.70710678118654752f));
    out[ob] = f2bf(ge * g);
  }
}

// ---------------- K8: pout GEMM + residual + BCHW scatter (f32 out), chunked ----------------
__global__ __launch_bounds__(256) void k8_pout(
    const __hip_bfloat16* __restrict__ A,    // gated (8192, 512)
    const __hip_bfloat16* __restrict__ B,    // padded pout_w bf16 (192, 512)
    const __hip_bfloat16* __restrict__ x2,   // (NTOK, 192)
    float* __restrict__ out,                 // (2,192,256,256) f32
    int b, int r0) {
  int wave = threadIdx.x >> 6, lane = threadIdx.x & 63;
  int m0 = blockIdx.y << 4;
  int n0 = (blockIdx.x * 4 + wave) << 4;
  int r16 = lane & 15, quad = lane >> 4;
  const __hip_bfloat16* Ap = A + (long)(m0 + r16) * 512 + quad * 8;
  const __hip_bfloat16* Bp = B + (long)(n0 + r16) * 512 + quad * 8;
  floatx4 acc = {0.f, 0.f, 0.f, 0.f};
  for (int k = 0; k < 512; k += 32) {
    bf16x8 a  = *(const bf16x8*)(Ap + k);
    bf16x8 bb = *(const bf16x8*)(Bp + k);
    acc = __builtin_amdgcn_mfma_f32_16x16x32_bf16(a, bb, acc, 0, 0, 0);
  }
  int col = n0 + r16;   // < 192 always
  for (int r = 0; r < 4; ++r) {
    int orow = m0 + quad * 4 + r;            // [0, 8192)
    int il = orow >> 8, j = orow & 255;
    long t = ((long)b << 16) + ((r0 + il) << 8) + j;
    float v = acc[r] + bf2f(x2[t * CDIM + col]);
    out[((long)(b * CDIM + col) << 16) + ((r0 + il) << 8) + j] = v;
  }
}

extern "C" void kernel_launch(void* const* d_in, const int* in_sizes, int n_in,
                              void* d_out, int out_size, void* d_ws, size_t ws_size,
                              hipStream_t stream) {
  const float* x       = (const float*)d_in[0];
  const float* norm1_w = (const float*)d_in[1];
  const float* norm1_b = (const float*)d_in[2];
  const float* qkv_w   = (const float*)d_in[3];
  const float* rpb     = (const float*)d_in[4];
  const float* proj_w  = (const float*)d_in[5];
  const float* proj_b  = (const float*)d_in[6];
  const float* norm2_w = (const float*)d_in[7];
  const float* norm2_b = (const float*)d_in[8];
  const float* pin_w   = (const float*)d_in[9];
  const float* dw_w    = (const float*)d_in[10];
  const float* pout_w  = (const float*)d_in[11];

  // Workspace layout (bytes), peak ~121.5 MB:
  //  [0, 50.33M)        ln1out (window order) -> projout -> pin/gated chunks
  //  [50.33M, 100.66M)  attnout (window order) -> x2 (token-major)
  //  [100.66M, 101.71M) LN2 stats (mean,rstd fp32 per token)
  //  [101.71M, 120.59M) qkv chunk (16384 x 576)
  //  [120.59M, 120.78M) padded pout_w bf16 (192 x 512)
  //  [120.78M, 121.47M) converted bf16 weights: qkv_w, proj_w, pin_w, norm2
  char* ws = (char*)d_ws;
  __hip_bfloat16* wsLN1 = (__hip_bfloat16*)(ws);
  __hip_bfloat16* wsATT = (__hip_bfloat16*)(ws + 50331648UL);
  __hip_bfloat16* wsX2  = (__hip_bfloat16*)(ws + 50331648UL);
  float*          wsST  = (float*)         (ws + 100663296UL);
  __hip_bfloat16* wsQKV = (__hip_bfloat16*)(ws + 101711872UL);
  __hip_bfloat16* wsPW  = (__hip_bfloat16*)(ws + 120586240UL);
  __hip_bfloat16* wsQW  = (__hip_bfloat16*)(ws + 120782848UL);   // 110592 el
  __hip_bfloat16* wsPJW = (__hip_bfloat16*)(ws + 121004032UL);   // 36864 el
  __hip_bfloat16* wsPIW = (__hip_bfloat16*)(ws + 121077760UL);   // 195840 el
  __hip_bfloat16* wsN2  = (__hip_bfloat16*)(ws + 121469440UL);   // 384 el
  __hip_bfloat16* wsPRJ = (__hip_bfloat16*)(ws);
  __hip_bfloat16* wsPIN = (__hip_bfloat16*)(ws);                 // 34*256*1020*2 = 17,756,160
  __hip_bfloat16* wsGT  = (__hip_bfloat16*)(ws + 17756160UL);    // 32*256*512*2  = 16,777,216
  float* out = (float*)d_out;

  // weight conversions f32 -> bf16
  kcvt<<<(110592 + 255) / 256, 256, 0, stream>>>(qkv_w, wsQW, 110592);
  kcvt<<<(36864 + 255) / 256, 256, 0, stream>>>(proj_w, wsPJW, 36864);
  kcvt<<<(195840 + 255) / 256, 256, 0, stream>>>(pin_w, wsPIW, 195840);
  kcvt<<<1, 256, 0, stream>>>(norm2_w, wsN2, 192);
  kcvt<<<1, 256, 0, stream>>>(norm2_b, wsN2 + 192, 192);
  k0_pad<<<384, 256, 0, stream>>>(pout_w, wsPW);
  // LN1 + shift + window partition -> wsLN1 (window token-major, 192)
  k1_ln_window<<<32768, 256, 0, stream>>>(x, norm1_w, norm1_b, wsLN1);
  // qkv GEMM + attention, chunked over 8 groups of 256 windows (16384 tokens)
  for (int c = 0; c < 8; ++c) {
    gemm_bt<0><<<dim3(9, 1024), 256, 0, stream>>>(
        wsLN1 + (long)c * 16384 * CDIM, wsQW, nullptr, wsQKV, 576, 192, 192, 192, 576);
    k3_attn<<<dim3(8, 256), 64, 0, stream>>>(wsQKV, rpb, wsATT, c * 256);
  }
  // proj GEMM (+bias): window order -> wsPRJ
  gemm_bt<1><<<dim3(3, 8192), 256, 0, stream>>>(wsATT, wsPJW, proj_b, wsPRJ, 192, 192, 192, 192, 192);
  // residual + unshift + LN2 stats -> wsX2 (token-major), wsST
  k4_resln<<<32768, 256, 0, stream>>>(x, wsPRJ, wsX2, wsST);
  // FFN, chunked: 16 chunks of 32 image rows (per batch), 1-row halo
  for (int cc = 0; cc < 16; ++cc) {
    int b = cc >> 3, r0 = (cc & 7) * 32;
    gemm_pin<<<dim3(16, 544), 256, 0, stream>>>(wsX2, wsST, wsN2, wsN2 + 192, wsPIW, wsPIN, b, r0);
    k7_dwgate<<<8192, 256, 0, stream>>>(wsPIN, dw_w, wsGT, r0);
    k8_pout<<<dim3(3, 512), 256, 0, stream>>>(wsGT, wsPW, wsX2, out, b, r0);
  }
}

// Round 4
// 2371.054 us; speedup vs baseline: 1.6739x; 1.6739x over previous
//
#include <hip/hip_runtime.h>
#include <hip/hip_bf16.h>
#include <math.h>

#define CDIM 192
#define NTOK 131072   /* B*H*W = 2*256*256 */
#define HD 24
#define NHEADS 8

typedef __attribute__((ext_vector_type(4))) float floatx4;
typedef __attribute__((ext_vector_type(8))) short bf16x8;

static __device__ __forceinline__ float bf2f(__hip_bfloat16 h) { return __bfloat162float(h); }
static __device__ __forceinline__ __hip_bfloat16 f2bf(float f) { return __float2bfloat16(f); }
static __device__ __forceinline__ float s2f(short s) {
  union { unsigned u; float f; } c; c.u = ((unsigned)(unsigned short)s) << 16; return c.f;
}
static __device__ __forceinline__ short f2s(float f) {
  __hip_bfloat16 h = __float2bfloat16(f);
  union { __hip_bfloat16 h; short s; } c; c.h = h; return c.s;
}
static __device__ __forceinline__ void load_lds16(const void* g, void* l) {
  __builtin_amdgcn_global_load_lds(
      (const __attribute__((address_space(1))) void*)g,
      (__attribute__((address_space(3))) void*)l, 16, 0, 0);
}

// ---------------- KC: f32 -> bf16 convert ----------------
__global__ __launch_bounds__(256) void kcvt(
    const float* __restrict__ in, __hip_bfloat16* __restrict__ out, int n) {
  int i = blockIdx.x * 256 + threadIdx.x;
  if (i < n) out[i] = f2bf(in[i]);
}

// ---------------- K0a: pad pout_w (192,510) f32 -> (192,512) bf16 ----------------
__global__ __launch_bounds__(256) void k0_padpout(
    const float* __restrict__ w, __hip_bfloat16* __restrict__ o) {
  int idx = blockIdx.x * 256 + threadIdx.x;   // 192*512
  int n = idx >> 9, k = idx & 511;
  o[idx] = (k < 510) ? f2bf(w[n * 510 + k]) : f2bf(0.f);
}

// ---------------- K0b: pad pin_w (1020,192) f32 -> (1024,192) bf16 ----------------
__global__ __launch_bounds__(256) void k0_padpin(
    const float* __restrict__ w, __hip_bfloat16* __restrict__ o) {
  int idx = blockIdx.x * 256 + threadIdx.x;   // 1024*192
  int n = idx / 192, k = idx % 192;
  o[idx] = (n < 1020) ? f2bf(w[n * 192 + k]) : f2bf(0.f);
}

// ---------------- K1: LN1 + shift + window partition (f32 in, bf16 out) ----------------
__global__ __launch_bounds__(256) void k1_ln_window(
    const float* __restrict__ x,
    const float* __restrict__ w,
    const float* __restrict__ bsh,
    __hip_bfloat16* __restrict__ out) {
  int wave = threadIdx.x >> 6, lane = threadIdx.x & 63;
  int t = blockIdx.x * 4 + wave;           // window-order token
  int wid = t >> 6, n = t & 63;
  int b = wid >> 10, wi = (wid >> 5) & 31, wj = wid & 31;
  int ti = n >> 3, tj = n & 7;
  int i = ((wi << 3) + ti + 4) & 255;      // unshifted row (roll -4)
  int j = ((wj << 3) + tj + 4) & 255;
  int pix = (i << 8) + j;
  int c0 = lane * 3;
  float v0 = x[((long)(b * CDIM + c0    ) << 16) + pix];
  float v1 = x[((long)(b * CDIM + c0 + 1) << 16) + pix];
  float v2 = x[((long)(b * CDIM + c0 + 2) << 16) + pix];
  float s = v0 + v1 + v2;
  float sq = v0 * v0 + v1 * v1 + v2 * v2;
  for (int off = 32; off; off >>= 1) { s += __shfl_xor(s, off); sq += __shfl_xor(sq, off); }
  float mean = s * (1.0f / 192.0f);
  float var  = sq * (1.0f / 192.0f) - mean * mean;
  float rstd = rsqrtf(var + 1e-5f);
  long base = (long)t * CDIM + c0;
  out[base    ] = f2bf((v0 - mean) * rstd * w[c0    ] + bsh[c0    ]);
  out[base + 1] = f2bf((v1 - mean) * rstd * w[c0 + 1] + bsh[c0 + 1]);
  out[base + 2] = f2bf((v2 - mean) * rstd * w[c0 + 2] + bsh[c0 + 2]);
}

// ---------------- LDS-staged MFMA GEMM: C(M,N) = A(M,K)*B(N,K)^T ----------------
// Block tile (32*WM) x (32*WN), 4 waves in 2x2, BK=32.
// M % (32*WM) == 0, N % (32*WN) == 0, K % 32 == 0 required.
// EPI: 0 plain, 1 +bias(f32)
template <int WM, int WN, int EPI>
__global__ __launch_bounds__(256) void gemm_lds(
    const __hip_bfloat16* __restrict__ A,
    const __hip_bfloat16* __restrict__ B,
    const float* __restrict__ bias,
    __hip_bfloat16* __restrict__ C,
    int K, int lda, int ldb, int ldc) {
  constexpr int BM = 32 * WM, BN = 32 * WN;
  __shared__ __hip_bfloat16 As[BM * 32];
  __shared__ __hip_bfloat16 Bs[BN * 32];
  int t = threadIdx.x;
  int wave = t >> 6, lane = t & 63;
  int wm = wave >> 1, wn = wave & 1;
  int r16 = lane & 15, quad = lane >> 4;
  long m0 = (long)blockIdx.y * BM;
  long n0 = (long)blockIdx.x * BN;
  int srow = t >> 2, scol = (t & 3) << 3;  // staging: 64 rows x 32 cols per pass
  floatx4 acc[WM][WN];
  for (int i = 0; i < WM; ++i)
    for (int j = 0; j < WN; ++j)
      acc[i][j] = (floatx4){0.f, 0.f, 0.f, 0.f};
  for (int k0 = 0; k0 < K; k0 += 32) {
    __syncthreads();
    for (int p = 0; p < WM / 2; ++p)
      load_lds16(A + (m0 + srow + p * 64) * lda + k0 + scol,
                 (char*)As + t * 16 + p * 4096);
    for (int p = 0; p < WN / 2; ++p)
      load_lds16(B + (n0 + srow + p * 64) * ldb + k0 + scol,
                 (char*)Bs + t * 16 + p * 4096);
    __syncthreads();
    bf16x8 af[WM], bf[WN];
    for (int i = 0; i < WM; ++i)
      af[i] = *(const bf16x8*)&As[(wm * 16 * WM + i * 16 + r16) * 32 + quad * 8];
    for (int j = 0; j < WN; ++j)
      bf[j] = *(const bf16x8*)&Bs[(wn * 16 * WN + j * 16 + r16) * 32 + quad * 8];
    for (int i = 0; i < WM; ++i)
      for (int j = 0; j < WN; ++j)
        acc[i][j] = __builtin_amdgcn_mfma_f32_16x16x32_bf16(af[i], bf[j], acc[i][j], 0, 0, 0);
  }
  for (int i = 0; i < WM; ++i)
    for (int j = 0; j < WN; ++j) {
      int col = n0 + wn * 16 * WN + j * 16 + r16;
      float badd = (EPI == 1) ? bias[col] : 0.f;
      for (int r = 0; r < 4; ++r) {
        long row = m0 + wm * 16 * WM + i * 16 + quad * 4 + r;
        C[row * ldc + col] = f2bf(acc[i][j][r] + badd);
      }
    }
}

// ---------------- pout GEMM (transposed output) + residual + coalesced f32 store ----
// "A" = padded pout_w (192,512); "B" = gated chunk (16384,512)
// C'(c, p) = sum_k A[c,k]*B[p,k]; out[b,c,r0+il,j] = C' + x2[t,c]
__global__ __launch_bounds__(256) void gemm_pout(
    const __hip_bfloat16* __restrict__ A,
    const __hip_bfloat16* __restrict__ B,
    const __hip_bfloat16* __restrict__ x2,
    float* __restrict__ out,
    int b, int r0) {
  constexpr int WM = 2, WN = 4, BM = 64, BN = 128;
  __shared__ __hip_bfloat16 As[BM * 32];
  __shared__ __hip_bfloat16 Bs[BN * 32];
  int t = threadIdx.x;
  int wave = t >> 6, lane = t & 63;
  int wm = wave >> 1, wn = wave & 1;
  int r16 = lane & 15, quad = lane >> 4;
  long m0 = (long)blockIdx.y * BM;     // channel block
  long n0 = (long)blockIdx.x * BN;     // pixel block
  int srow = t >> 2, scol = (t & 3) << 3;
  floatx4 acc[WM][WN];
  for (int i = 0; i < WM; ++i)
    for (int j = 0; j < WN; ++j)
      acc[i][j] = (floatx4){0.f, 0.f, 0.f, 0.f};
  for (int k0 = 0; k0 < 512; k0 += 32) {
    __syncthreads();
    load_lds16(A + (m0 + srow) * 512 + k0 + scol, (char*)As + t * 16);
    for (int p = 0; p < WN / 2; ++p)
      load_lds16(B + (n0 + srow + p * 64) * 512 + k0 + scol,
                 (char*)Bs + t * 16 + p * 4096);
    __syncthreads();
    bf16x8 af[WM], bf[WN];
    for (int i = 0; i < WM; ++i)
      af[i] = *(const bf16x8*)&As[(wm * 16 * WM + i * 16 + r16) * 32 + quad * 8];
    for (int j = 0; j < WN; ++j)
      bf[j] = *(const bf16x8*)&Bs[(wn * 16 * WN + j * 16 + r16) * 32 + quad * 8];
    for (int i = 0; i < WM; ++i)
      for (int j = 0; j < WN; ++j)
        acc[i][j] = __builtin_amdgcn_mfma_f32_16x16x32_bf16(af[i], bf[j], acc[i][j], 0, 0, 0);
  }
  for (int i = 0; i < WM; ++i)
    for (int j = 0; j < WN; ++j) {
      int p_ = n0 + wn * 16 * WN + j * 16 + r16;     // pixel in chunk [0,16384)
      int il = p_ >> 8, jj = p_ & 255;
      long pix = ((long)(r0 + il) << 8) + jj;
      for (int r = 0; r < 4; ++r) {
        int c_ = m0 + wm * 16 * WM + i * 16 + quad * 4 + r;  // channel < 192
        long tok = ((long)b << 16) + pix;
        float v = acc[i][j][r] + bf2f(x2[tok * CDIM + c_]);
        out[((long)(b * CDIM + c_) << 16) + pix] = v;
      }
    }
}

// ---------------- K3: window attention, one block per (head, window-in-chunk) ----------------
__global__ __launch_bounds__(64) void k3_attn(
    const __hip_bfloat16* __restrict__ qkv,   // chunk base, stride 576, 256 windows
    const float* __restrict__ rpb,
    __hip_bfloat16* __restrict__ out,         // full attnout (NTOK,192)
    int wid0) {
  __shared__ float kk[64][HD + 1];
  __shared__ float vv[64][HD + 1];
  int h = blockIdx.x, widl = blockIdx.y;
  int wid = wid0 + widl;                      // global window id
  int n = threadIdx.x;
  long tb = (long)(widl * 64 + n) * 576 + h * HD;
  for (int d = 0; d < HD; ++d) {
    kk[n][d] = bf2f(qkv[tb + 192 + d]);
    vv[n][d] = bf2f(qkv[tb + 384 + d]);
  }
  float q[HD];
  for (int d = 0; d < HD; ++d) q[d] = bf2f(qkv[tb + d]) * 0.20412414523193154f;
  __syncthreads();
  int wi = (wid >> 5) & 31, wj = wid & 31;
  int ti = n >> 3, tj = n & 7;
  int gi = wi * 8 + ti, gj = wj * 8 + tj;
  int rq = ((gi < 248) ? 0 : (gi < 252 ? 1 : 2)) * 3 + ((gj < 248) ? 0 : (gj < 252 ? 1 : 2));
  float s[64];
  float mx = -1e30f;
  for (int m = 0; m < 64; ++m) {
    float acc = 0.f;
    for (int d = 0; d < HD; ++d) acc += q[d] * kk[m][d];
    int si = m >> 3, sj = m & 7;
    int idx = (ti - si + 7) * 15 + (tj - sj + 7);
    acc += rpb[idx * NHEADS + h];
    int gsi = wi * 8 + si, gsj = wj * 8 + sj;
    int rk = ((gsi < 248) ? 0 : (gsi < 252 ? 1 : 2)) * 3 + ((gsj < 248) ? 0 : (gsj < 252 ? 1 : 2));
    if (rk != rq) acc -= 100.0f;
    s[m] = acc;
    mx = fmaxf(mx, acc);
  }
  float sum = 0.f;
  for (int m = 0; m < 64; ++m) { s[m] = expf(s[m] - mx); sum += s[m]; }
  float rs = 1.0f / sum;
  long ob = (long)(wid * 64 + n) * CDIM + h * HD;
  for (int d = 0; d < HD; ++d) {
    float acc = 0.f;
    for (int m = 0; m < 64; ++m) acc += s[m] * vv[m][d];
    out[ob + d] = f2bf(acc * rs);
  }
}

// ---------------- K4: residual + unshift scatter + LN2 stats ----------------
__global__ __launch_bounds__(256) void k4_resln(
    const float* __restrict__ x,
    const __hip_bfloat16* __restrict__ tmp,   // proj out, window order
    __hip_bfloat16* __restrict__ x2,          // unshifted token-major (NTOK,192)
    float* __restrict__ stats) {              // (NTOK,2): mean, rstd
  int wave = threadIdx.x >> 6, lane = threadIdx.x & 63;
  int t = blockIdx.x * 4 + wave;
  int wid = t >> 6, n = t & 63;
  int b = wid >> 10, wi = (wid >> 5) & 31, wj = wid & 31;
  int ti = n >> 3, tj = n & 7;
  int i = ((wi << 3) + ti + 4) & 255;
  int j = ((wj << 3) + tj + 4) & 255;
  int pix = (i << 8) + j;
  long t2 = ((long)b << 16) + pix;
  int c0 = lane * 3;
  long tb = (long)t * CDIM + c0;
  float v0 = x[((long)(b * CDIM + c0    ) << 16) + pix] + bf2f(tmp[tb    ]);
  float v1 = x[((long)(b * CDIM + c0 + 1) << 16) + pix] + bf2f(tmp[tb + 1]);
  float v2 = x[((long)(b * CDIM + c0 + 2) << 16) + pix] + bf2f(tmp[tb + 2]);
  long ob = t2 * CDIM + c0;
  x2[ob] = f2bf(v0); x2[ob + 1] = f2bf(v1); x2[ob + 2] = f2bf(v2);
  float s = v0 + v1 + v2, sq = v0 * v0 + v1 * v1 + v2 * v2;
  for (int off = 32; off; off >>= 1) { s += __shfl_xor(s, off); sq += __shfl_xor(sq, off); }
  float mean = s * (1.0f / 192.0f);
  float var  = sq * (1.0f / 192.0f) - mean * mean;
  float rstd = rsqrtf(var + 1e-5f);
  if (lane == 0) { stats[2 * t2] = mean; stats[2 * t2 + 1] = rstd; }
}

// ---------------- K5: materialize LN2 chunk (66 rows w/ halo, bf16) ----------------
__global__ __launch_bounds__(256) void k5_ln2(
    const __hip_bfloat16* __restrict__ x2,
    const float* __restrict__ stats,
    const float* __restrict__ nw,
    const float* __restrict__ nb,
    __hip_bfloat16* __restrict__ out,        // (66*256, 192)
    int b, int r0) {
  int idx = blockIdx.x * 256 + threadIdx.x;  // [0, 16896*24)
  int tok = idx / 24, c0 = (idx % 24) << 3;
  int il = tok >> 8, j = tok & 255;
  int gi = r0 - 1 + il; gi = gi < 0 ? 0 : (gi > 255 ? 255 : gi);
  long t = ((long)b << 16) + (gi << 8) + j;
  float mean = stats[2 * t], rstd = stats[2 * t + 1];
  bf16x8 v = *(const bf16x8*)((const short*)x2 + t * CDIM + c0);
  bf16x8 r;
  for (int e = 0; e < 8; ++e)
    r[e] = f2s((s2f(v[e]) - mean) * rstd * nw[c0 + e] + nb[c0 + e]);
  *(bf16x8*)((short*)out + (long)tok * CDIM + c0) = r;
}

// ---------------- K7: depthwise 3x3 + gated exact GELU, 64-row chunk ----------------
__global__ __launch_bounds__(256) void k7_dwgate(
    const __hip_bfloat16* __restrict__ pin,  // (66*256, 1024) chunk (rows r0-1..r0+64 clamped)
    const float* __restrict__ wdw,           // (1020, 9) f32
    __hip_bfloat16* __restrict__ out,        // (16384, 512) zero-padded cols 510,511
    int r0) {
  int p = blockIdx.x;                        // [0, 16384): 64 rows x 256 cols
  int il = p >> 8, j = p & 255;
  int gi = r0 + il;
  for (int it = 0; it < 2; ++it) {
    int hc = threadIdx.x + it * 256;
    long ob = (long)p * 512 + hc;
    if (hc >= 510) { out[ob] = f2bf(0.f); continue; }
    float a = 0.f, g = 0.f;
    for (int di = -1; di <= 1; ++di) {
      int ii = gi + di; if (ii < 0 || ii > 255) continue;
      int br = il + di + 1;                  // [0, 66)
      for (int dj = -1; dj <= 1; ++dj) {
        int jj = j + dj; if (jj < 0 || jj > 255) continue;
        long nbase = ((long)((br << 8) + jj)) << 10;   // *1024
        int widx = (di + 1) * 3 + (dj + 1);
        a += wdw[hc * 9 + widx]         * bf2f(pin[nbase + hc]);
        g += wdw[(hc + 510) * 9 + widx] * bf2f(pin[nbase + hc + 510]);
      }
    }
    float ge = 0.5f * a * (1.0f + erff(a * 0.70710678118654752f));
    out[ob] = f2bf(ge * g);
  }
}

extern "C" void kernel_launch(void* const* d_in, const int* in_sizes, int n_in,
                              void* d_out, int out_size, void* d_ws, size_t ws_size,
                              hipStream_t stream) {
  const float* x       = (const float*)d_in[0];
  const float* norm1_w = (const float*)d_in[1];
  const float* norm1_b = (const float*)d_in[2];
  const float* qkv_w   = (const float*)d_in[3];
  const float* rpb     = (const float*)d_in[4];
  const float* proj_w  = (const float*)d_in[5];
  const float* proj_b  = (const float*)d_in[6];
  const float* norm2_w = (const float*)d_in[7];
  const float* norm2_b = (const float*)d_in[8];
  const float* pin_w   = (const float*)d_in[9];
  const float* dw_w    = (const float*)d_in[10];
  const float* pout_w  = (const float*)d_in[11];

  // Workspace layout (bytes), peak ~121.5 MB (same footprint as passing round):
  //  [0, 50.33M)          ln1out / projout ; later pin-chunk C (16896x1024) + ln2 chunk
  //  [50.33M, 100.66M)    attnout (window order) -> x2 (token-major)
  //  [100.66M, 101.71M)   LN2 stats (mean,rstd fp32 per token)
  //  [101.71M, 120.59M)   qkv chunk (16384x576) ; later gated chunk (16384x512)
  //  [120.59M, 121.47M)   padded pout_w, qkv_w bf16, proj_w bf16, padded pin_w bf16
  char* ws = (char*)d_ws;
  __hip_bfloat16* wsLN1 = (__hip_bfloat16*)(ws);
  __hip_bfloat16* wsPRJ = (__hip_bfloat16*)(ws);
  __hip_bfloat16* wsPINC= (__hip_bfloat16*)(ws);                  // 16896*1024*2 = 34,603,008
  __hip_bfloat16* wsLN2C= (__hip_bfloat16*)(ws + 34603008UL);     // 16896*192*2  =  6,488,064
  __hip_bfloat16* wsATT = (__hip_bfloat16*)(ws + 50331648UL);
  __hip_bfloat16* wsX2  = (__hip_bfloat16*)(ws + 50331648UL);
  float*          wsST  = (float*)         (ws + 100663296UL);
  __hip_bfloat16* wsQKV = (__hip_bfloat16*)(ws + 101711872UL);
  __hip_bfloat16* wsGT  = (__hip_bfloat16*)(ws + 101711872UL);    // 16384*512*2 = 16,777,216
  __hip_bfloat16* wsPW  = (__hip_bfloat16*)(ws + 120586240UL);    // 192*512
  __hip_bfloat16* wsQW  = (__hip_bfloat16*)(ws + 120782848UL);    // 110592
  __hip_bfloat16* wsPJW = (__hip_bfloat16*)(ws + 121004032UL);    // 36864
  __hip_bfloat16* wsPIW = (__hip_bfloat16*)(ws + 121077760UL);    // 1024*192 = 196608
  float* out = (float*)d_out;

  // weight conversion / padding
  kcvt<<<(110592 + 255) / 256, 256, 0, stream>>>(qkv_w, wsQW, 110592);
  kcvt<<<(36864 + 255) / 256, 256, 0, stream>>>(proj_w, wsPJW, 36864);
  k0_padpout<<<384, 256, 0, stream>>>(pout_w, wsPW);
  k0_padpin<<<768, 256, 0, stream>>>(pin_w, wsPIW);
  // LN1 + shift + window partition -> wsLN1 (window token-major, 192)
  k1_ln_window<<<32768, 256, 0, stream>>>(x, norm1_w, norm1_b, wsLN1);
  // qkv GEMM + attention, 8 chunks of 256 windows (16384 tokens)
  for (int c = 0; c < 8; ++c) {
    gemm_lds<4, 2, 0><<<dim3(9, 128), 256, 0, stream>>>(
        wsLN1 + (long)c * 16384 * CDIM, wsQW, nullptr, wsQKV, 192, 192, 192, 576);
    k3_attn<<<dim3(8, 256), 64, 0, stream>>>(wsQKV, rpb, wsATT, c * 256);
  }
  // proj GEMM (+bias): window order -> wsPRJ
  gemm_lds<4, 2, 1><<<dim3(3, 1024), 256, 0, stream>>>(
      wsATT, wsPJW, proj_b, wsPRJ, 192, 192, 192, 192);
  // residual + unshift + LN2 stats -> wsX2 (token-major), wsST
  k4_resln<<<32768, 256, 0, stream>>>(x, wsPRJ, wsX2, wsST);
  // FFN, 8 chunks of 64 image rows (per batch), 1-row halo
  for (int cc = 0; cc < 8; ++cc) {
    int b = cc >> 2, r0 = (cc & 3) * 64;
    k5_ln2<<<1584, 256, 0, stream>>>(wsX2, wsST, norm2_w, norm2_b, wsLN2C, b, r0);
    gemm_lds<4, 2, 0><<<dim3(16, 132), 256, 0, stream>>>(
        wsLN2C, wsPIW, nullptr, wsPINC, 192, 192, 192, 1024);
    k7_dwgate<<<16384, 256, 0, stream>>>(wsPINC, dw_w, wsGT, r0);
    gemm_pout<<<dim3(128, 3), 256, 0, stream>>>(wsPW, wsGT, wsX2, out, b, r0);
  }
}

// Round 5
// 1376.010 us; speedup vs baseline: 2.8844x; 1.7231x over previous
//
#include <hip/hip_runtime.h>
#include <hip/hip_bf16.h>
#include <math.h>

#define CDIM 192
#define NTOK 131072   /* B*H*W = 2*256*256 */
#define HD 24
#define NHEADS 8

typedef __attribute__((ext_vector_type(4))) float floatx4;
typedef __attribute__((ext_vector_type(8))) short bf16x8;

static __device__ __forceinline__ float bf2f(__hip_bfloat16 h) { return __bfloat162float(h); }
static __device__ __forceinline__ __hip_bfloat16 f2bf(float f) { return __float2bfloat16(f); }
static __device__ __forceinline__ float s2f(short s) {
  union { unsigned u; float f; } c; c.u = ((unsigned)(unsigned short)s) << 16; return c.f;
}
static __device__ __forceinline__ short f2s(float f) {
  __hip_bfloat16 h = __float2bfloat16(f);
  union { __hip_bfloat16 h; short s; } c; c.h = h; return c.s;
}
static __device__ __forceinline__ void load_lds16(const void* g, void* l) {
  __builtin_amdgcn_global_load_lds(
      (const __attribute__((address_space(1))) void*)g,
      (__attribute__((address_space(3))) void*)l, 16, 0, 0);
}

// ---------------- KC: f32 -> bf16 convert ----------------
__global__ __launch_bounds__(256) void kcvt(
    const float* __restrict__ in, __hip_bfloat16* __restrict__ out, int n) {
  int i = blockIdx.x * 256 + threadIdx.x;
  if (i < n) out[i] = f2bf(in[i]);
}

// ---------------- K0a: pad pout_w (192,510) f32 -> (192,512) bf16 ----------------
__global__ __launch_bounds__(256) void k0_padpout(
    const float* __restrict__ w, __hip_bfloat16* __restrict__ o) {
  int idx = blockIdx.x * 256 + threadIdx.x;   // 192*512
  int n = idx >> 9, k = idx & 511;
  o[idx] = (k < 510) ? f2bf(w[n * 510 + k]) : f2bf(0.f);
}

// ---------------- K0b: pad pin_w (1020,192) f32 -> (1024,192) bf16 ----------------
// a-part rows 0..509 -> 0..509 (pad 510,511); g-part rows 510..1019 -> 512..1021 (pad 1022,1023)
__global__ __launch_bounds__(256) void k0_padpin(
    const float* __restrict__ w, __hip_bfloat16* __restrict__ o) {
  int idx = blockIdx.x * 256 + threadIdx.x;   // 1024*192
  int n = idx / 192, k = idx % 192;
  int src = (n < 510) ? n : ((n >= 512 && n < 1022) ? n - 2 : -1);
  o[idx] = (src >= 0) ? f2bf(w[src * 192 + k]) : f2bf(0.f);
}

// ---------------- K0c: transpose dw_w (1020,9) f32 -> tap-major bf16 WA[9][512], WG[9][512] ---
__global__ __launch_bounds__(256) void k0_wtap(
    const float* __restrict__ wdw, __hip_bfloat16* __restrict__ wa,
    __hip_bfloat16* __restrict__ wg) {
  int idx = blockIdx.x * 256 + threadIdx.x;   // 9*512
  if (idx >= 9 * 512) return;
  int tap = idx >> 9, c = idx & 511;
  wa[idx] = (c < 510) ? f2bf(wdw[c * 9 + tap]) : f2bf(0.f);
  wg[idx] = (c < 510) ? f2bf(wdw[(c + 510) * 9 + tap]) : f2bf(0.f);
}

// ---------------- K1: LN1 + shift + window partition (f32 in, bf16 out) ----------------
__global__ __launch_bounds__(256) void k1_ln_window(
    const float* __restrict__ x,
    const float* __restrict__ w,
    const float* __restrict__ bsh,
    __hip_bfloat16* __restrict__ out) {
  int wave = threadIdx.x >> 6, lane = threadIdx.x & 63;
  int t = blockIdx.x * 4 + wave;           // window-order token
  int wid = t >> 6, n = t & 63;
  int b = wid >> 10, wi = (wid >> 5) & 31, wj = wid & 31;
  int ti = n >> 3, tj = n & 7;
  int i = ((wi << 3) + ti + 4) & 255;      // unshifted row (roll -4)
  int j = ((wj << 3) + tj + 4) & 255;
  int pix = (i << 8) + j;
  int c0 = lane * 3;
  float v0 = x[((long)(b * CDIM + c0    ) << 16) + pix];
  float v1 = x[((long)(b * CDIM + c0 + 1) << 16) + pix];
  float v2 = x[((long)(b * CDIM + c0 + 2) << 16) + pix];
  float s = v0 + v1 + v2;
  float sq = v0 * v0 + v1 * v1 + v2 * v2;
  for (int off = 32; off; off >>= 1) { s += __shfl_xor(s, off); sq += __shfl_xor(sq, off); }
  float mean = s * (1.0f / 192.0f);
  float var  = sq * (1.0f / 192.0f) - mean * mean;
  float rstd = rsqrtf(var + 1e-5f);
  long base = (long)t * CDIM + c0;
  out[base    ] = f2bf((v0 - mean) * rstd * w[c0    ] + bsh[c0    ]);
  out[base + 1] = f2bf((v1 - mean) * rstd * w[c0 + 1] + bsh[c0 + 1]);
  out[base + 2] = f2bf((v2 - mean) * rstd * w[c0 + 2] + bsh[c0 + 2]);
}

// ---------------- LDS-staged MFMA GEMM: C(M,N) = A(M,K)*B(N,K)^T ----------------
// Block tile (32*WM) x (32*WN), 4 waves in 2x2, BK=32.
// M % (32*WM) == 0, N % (32*WN) == 0, K % 32 == 0 required.
// EPI: 0 plain, 1 +bias(f32)
template <int WM, int WN, int EPI>
__global__ __launch_bounds__(256) void gemm_lds(
    const __hip_bfloat16* __restrict__ A,
    const __hip_bfloat16* __restrict__ B,
    const float* __restrict__ bias,
    __hip_bfloat16* __restrict__ C,
    int K, int lda, int ldb, int ldc) {
  constexpr int BM = 32 * WM, BN = 32 * WN;
  __shared__ __hip_bfloat16 As[BM * 32];
  __shared__ __hip_bfloat16 Bs[BN * 32];
  int t = threadIdx.x;
  int wave = t >> 6, lane = t & 63;
  int wm = wave >> 1, wn = wave & 1;
  int r16 = lane & 15, quad = lane >> 4;
  long m0 = (long)blockIdx.y * BM;
  long n0 = (long)blockIdx.x * BN;
  int srow = t >> 2, scol = (t & 3) << 3;  // staging: 64 rows x 32 cols per pass
  floatx4 acc[WM][WN];
  for (int i = 0; i < WM; ++i)
    for (int j = 0; j < WN; ++j)
      acc[i][j] = (floatx4){0.f, 0.f, 0.f, 0.f};
  for (int k0 = 0; k0 < K; k0 += 32) {
    __syncthreads();
    for (int p = 0; p < WM / 2; ++p)
      load_lds16(A + (m0 + srow + p * 64) * lda + k0 + scol,
                 (char*)As + t * 16 + p * 4096);
    for (int p = 0; p < WN / 2; ++p)
      load_lds16(B + (n0 + srow + p * 64) * ldb + k0 + scol,
                 (char*)Bs + t * 16 + p * 4096);
    __syncthreads();
    bf16x8 af[WM], bf[WN];
    for (int i = 0; i < WM; ++i)
      af[i] = *(const bf16x8*)&As[(wm * 16 * WM + i * 16 + r16) * 32 + quad * 8];
    for (int j = 0; j < WN; ++j)
      bf[j] = *(const bf16x8*)&Bs[(wn * 16 * WN + j * 16 + r16) * 32 + quad * 8];
    for (int i = 0; i < WM; ++i)
      for (int j = 0; j < WN; ++j)
        acc[i][j] = __builtin_amdgcn_mfma_f32_16x16x32_bf16(af[i], bf[j], acc[i][j], 0, 0, 0);
  }
  for (int i = 0; i < WM; ++i)
    for (int j = 0; j < WN; ++j) {
      int col = n0 + wn * 16 * WN + j * 16 + r16;
      float badd = (EPI == 1) ? bias[col] : 0.f;
      for (int r = 0; r < 4; ++r) {
        long row = m0 + wm * 16 * WM + i * 16 + quad * 4 + r;
        C[row * ldc + col] = f2bf(acc[i][j][r] + badd);
      }
    }
}

// ---------------- pout GEMM (transposed output) + residual + coalesced f32 store ----
__global__ __launch_bounds__(256) void gemm_pout(
    const __hip_bfloat16* __restrict__ A,    // padded pout_w (192,512)
    const __hip_bfloat16* __restrict__ B,    // gated chunk (16384,512)
    const __hip_bfloat16* __restrict__ x2,
    float* __restrict__ out,
    int b, int r0) {
  constexpr int WM = 2, WN = 4, BM = 64, BN = 128;
  __shared__ __hip_bfloat16 As[BM * 32];
  __shared__ __hip_bfloat16 Bs[BN * 32];
  int t = threadIdx.x;
  int wave = t >> 6, lane = t & 63;
  int wm = wave >> 1, wn = wave & 1;
  int r16 = lane & 15, quad = lane >> 4;
  long m0 = (long)blockIdx.y * BM;     // channel block
  long n0 = (long)blockIdx.x * BN;     // pixel block
  int srow = t >> 2, scol = (t & 3) << 3;
  floatx4 acc[WM][WN];
  for (int i = 0; i < WM; ++i)
    for (int j = 0; j < WN; ++j)
      acc[i][j] = (floatx4){0.f, 0.f, 0.f, 0.f};
  for (int k0 = 0; k0 < 512; k0 += 32) {
    __syncthreads();
    load_lds16(A + (m0 + srow) * 512 + k0 + scol, (char*)As + t * 16);
    for (int p = 0; p < WN / 2; ++p)
      load_lds16(B + (n0 + srow + p * 64) * 512 + k0 + scol,
                 (char*)Bs + t * 16 + p * 4096);
    __syncthreads();
    bf16x8 af[WM], bf[WN];
    for (int i = 0; i < WM; ++i)
      af[i] = *(const bf16x8*)&As[(wm * 16 * WM + i * 16 + r16) * 32 + quad * 8];
    for (int j = 0; j < WN; ++j)
      bf[j] = *(const bf16x8*)&Bs[(wn * 16 * WN + j * 16 + r16) * 32 + quad * 8];
    for (int i = 0; i < WM; ++i)
      for (int j = 0; j < WN; ++j)
        acc[i][j] = __builtin_amdgcn_mfma_f32_16x16x32_bf16(af[i], bf[j], acc[i][j], 0, 0, 0);
  }
  for (int i = 0; i < WM; ++i)
    for (int j = 0; j < WN; ++j) {
      int p_ = n0 + wn * 16 * WN + j * 16 + r16;     // pixel in chunk [0,16384)
      int il = p_ >> 8, jj = p_ & 255;
      long pix = ((long)(r0 + il) << 8) + jj;
      for (int r = 0; r < 4; ++r) {
        int c_ = m0 + wm * 16 * WM + i * 16 + quad * 4 + r;  // channel < 192
        long tok = ((long)b << 16) + pix;
        float v = acc[i][j][r] + bf2f(x2[tok * CDIM + c_]);
        out[((long)(b * CDIM + c_) << 16) + pix] = v;
      }
    }
}

// ---------------- K3: window attention, one block per (head, window-in-chunk) ----------------
__global__ __launch_bounds__(64) void k3_attn(
    const __hip_bfloat16* __restrict__ qkv,   // chunk base, stride 576, 256 windows
    const float* __restrict__ rpb,
    __hip_bfloat16* __restrict__ out,         // full attnout (NTOK,192)
    int wid0) {
  __shared__ float kk[64][HD + 1];
  __shared__ float vv[64][HD + 1];
  int h = blockIdx.x, widl = blockIdx.y;
  int wid = wid0 + widl;                      // global window id
  int n = threadIdx.x;
  long tb = (long)(widl * 64 + n) * 576 + h * HD;
  for (int d = 0; d < HD; ++d) {
    kk[n][d] = bf2f(qkv[tb + 192 + d]);
    vv[n][d] = bf2f(qkv[tb + 384 + d]);
  }
  float q[HD];
  for (int d = 0; d < HD; ++d) q[d] = bf2f(qkv[tb + d]) * 0.20412414523193154f;
  __syncthreads();
  int wi = (wid >> 5) & 31, wj = wid & 31;
  int ti = n >> 3, tj = n & 7;
  int gi = wi * 8 + ti, gj = wj * 8 + tj;
  int rq = ((gi < 248) ? 0 : (gi < 252 ? 1 : 2)) * 3 + ((gj < 248) ? 0 : (gj < 252 ? 1 : 2));
  float s[64];
  float mx = -1e30f;
  for (int m = 0; m < 64; ++m) {
    float acc = 0.f;
    for (int d = 0; d < HD; ++d) acc += q[d] * kk[m][d];
    int si = m >> 3, sj = m & 7;
    int idx = (ti - si + 7) * 15 + (tj - sj + 7);
    acc += rpb[idx * NHEADS + h];
    int gsi = wi * 8 + si, gsj = wj * 8 + sj;
    int rk = ((gsi < 248) ? 0 : (gsi < 252 ? 1 : 2)) * 3 + ((gsj < 248) ? 0 : (gsj < 252 ? 1 : 2));
    if (rk != rq) acc -= 100.0f;
    s[m] = acc;
    mx = fmaxf(mx, acc);
  }
  float sum = 0.f;
  for (int m = 0; m < 64; ++m) { s[m] = expf(s[m] - mx); sum += s[m]; }
  float rs = 1.0f / sum;
  long ob = (long)(wid * 64 + n) * CDIM + h * HD;
  for (int d = 0; d < HD; ++d) {
    float acc = 0.f;
    for (int m = 0; m < 64; ++m) acc += s[m] * vv[m][d];
    out[ob + d] = f2bf(acc * rs);
  }
}

// ---------------- K4: residual + unshift scatter + LN2 stats ----------------
__global__ __launch_bounds__(256) void k4_resln(
    const float* __restrict__ x,
    const __hip_bfloat16* __restrict__ tmp,   // proj out, window order
    __hip_bfloat16* __restrict__ x2,          // unshifted token-major (NTOK,192)
    float* __restrict__ stats) {              // (NTOK,2): mean, rstd
  int wave = threadIdx.x >> 6, lane = threadIdx.x & 63;
  int t = blockIdx.x * 4 + wave;
  int wid = t >> 6, n = t & 63;
  int b = wid >> 10, wi = (wid >> 5) & 31, wj = wid & 31;
  int ti = n >> 3, tj = n & 7;
  int i = ((wi << 3) + ti + 4) & 255;
  int j = ((wj << 3) + tj + 4) & 255;
  int pix = (i << 8) + j;
  long t2 = ((long)b << 16) + pix;
  int c0 = lane * 3;
  long tb = (long)t * CDIM + c0;
  float v0 = x[((long)(b * CDIM + c0    ) << 16) + pix] + bf2f(tmp[tb    ]);
  float v1 = x[((long)(b * CDIM + c0 + 1) << 16) + pix] + bf2f(tmp[tb + 1]);
  float v2 = x[((long)(b * CDIM + c0 + 2) << 16) + pix] + bf2f(tmp[tb + 2]);
  long ob = t2 * CDIM + c0;
  x2[ob] = f2bf(v0); x2[ob + 1] = f2bf(v1); x2[ob + 2] = f2bf(v2);
  float s = v0 + v1 + v2, sq = v0 * v0 + v1 * v1 + v2 * v2;
  for (int off = 32; off; off >>= 1) { s += __shfl_xor(s, off); sq += __shfl_xor(sq, off); }
  float mean = s * (1.0f / 192.0f);
  float var  = sq * (1.0f / 192.0f) - mean * mean;
  float rstd = rsqrtf(var + 1e-5f);
  if (lane == 0) { stats[2 * t2] = mean; stats[2 * t2 + 1] = rstd; }
}

// ---------------- K5: materialize LN2 chunk (66 rows w/ halo, bf16) ----------------
__global__ __launch_bounds__(256) void k5_ln2(
    const __hip_bfloat16* __restrict__ x2,
    const float* __restrict__ stats,
    const float* __restrict__ nw,
    const float* __restrict__ nb,
    __hip_bfloat16* __restrict__ out,        // (66*256, 192)
    int b, int r0) {
  int idx = blockIdx.x * 256 + threadIdx.x;  // [0, 16896*24)
  int tok = idx / 24, c0 = (idx % 24) << 3;
  int il = tok >> 8, j = tok & 255;
  int gi = r0 - 1 + il; gi = gi < 0 ? 0 : (gi > 255 ? 255 : gi);
  long t = ((long)b << 16) + (gi << 8) + j;
  float mean = stats[2 * t], rstd = stats[2 * t + 1];
  bf16x8 v = *(const bf16x8*)((const short*)x2 + t * CDIM + c0);
  bf16x8 r;
  for (int e = 0; e < 8; ++e)
    r[e] = f2s((s2f(v[e]) - mean) * rstd * nw[c0 + e] + nb[c0 + e]);
  *(bf16x8*)((short*)out + (long)tok * CDIM + c0) = r;
}

// ---------------- K7v2: depthwise 3x3 + gated exact GELU, vectorized x8 ----------------
// pin: (66*256, 1024), a in cols [0,512), g in cols [512,1024)
// thread = (channel octet, pixel lane); block covers 4 pixels x 64 octets
__global__ __launch_bounds__(256) void k7_dwgate(
    const __hip_bfloat16* __restrict__ pin,
    const __hip_bfloat16* __restrict__ wa,   // (9,512) tap-major bf16
    const __hip_bfloat16* __restrict__ wg,   // (9,512)
    __hip_bfloat16* __restrict__ out,        // (16384, 512)
    int r0) {
  int t = threadIdx.x;
  int oct = t & 63, pl = t >> 6;
  int p = blockIdx.x * 4 + pl;               // [0, 16384)
  int il = p >> 8, j = p & 255;
  int gi = r0 + il;
  int c0 = oct << 3;
  float a[8], g[8];
  for (int e = 0; e < 8; ++e) { a[e] = 0.f; g[e] = 0.f; }
  for (int di = -1; di <= 1; ++di) {
    int ii = gi + di; if (ii < 0 || ii > 255) continue;
    int br = il + di + 1;                    // [0, 66)
    for (int dj = -1; dj <= 1; ++dj) {
      int jj = j + dj; if (jj < 0 || jj > 255) continue;
      long nbase = ((long)((br << 8) + jj)) << 10;   // *1024
      int tap = (di + 1) * 3 + (dj + 1);
      bf16x8 va  = *(const bf16x8*)((const short*)pin + nbase + c0);
      bf16x8 vg  = *(const bf16x8*)((const short*)pin + nbase + 512 + c0);
      bf16x8 wa8 = *(const bf16x8*)((const short*)wa + tap * 512 + c0);
      bf16x8 wg8 = *(const bf16x8*)((const short*)wg + tap * 512 + c0);
      for (int e = 0; e < 8; ++e) {
        a[e] += s2f(wa8[e]) * s2f(va[e]);
        g[e] += s2f(wg8[e]) * s2f(vg[e]);
      }
    }
  }
  bf16x8 r;
  for (int e = 0; e < 8; ++e) {
    float ge = 0.5f * a[e] * (1.0f + erff(a[e] * 0.70710678118654752f));
    r[e] = f2s(ge * g[e]);
  }
  *(bf16x8*)((short*)out + (long)p * 512 + c0) = r;
}

extern "C" void kernel_launch(void* const* d_in, const int* in_sizes, int n_in,
                              void* d_out, int out_size, void* d_ws, size_t ws_size,
                              hipStream_t stream) {
  const float* x       = (const float*)d_in[0];
  const float* norm1_w = (const float*)d_in[1];
  const float* norm1_b = (const float*)d_in[2];
  const float* qkv_w   = (const float*)d_in[3];
  const float* rpb     = (const float*)d_in[4];
  const float* proj_w  = (const float*)d_in[5];
  const float* proj_b  = (const float*)d_in[6];
  const float* norm2_w = (const float*)d_in[7];
  const float* norm2_b = (const float*)d_in[8];
  const float* pin_w   = (const float*)d_in[9];
  const float* dw_w    = (const float*)d_in[10];
  const float* pout_w  = (const float*)d_in[11];

  // Workspace layout (bytes), peak ~121.5 MB (same footprint as passing round):
  //  [0, 50.33M)          ln1out / projout ; later pin-chunk C (16896x1024) + ln2 chunk
  //  [50.33M, 100.66M)    attnout (window order) -> x2 (token-major)
  //  [100.66M, 101.71M)   LN2 stats (mean,rstd fp32 per token)
  //  [101.71M, 120.59M)   qkv chunk (16384x576) ; FFN phase: gated chunk (16384x512) + WA/WG
  //  [120.59M, 121.47M)   padded pout_w, qkv_w bf16, proj_w bf16, padded pin_w bf16
  char* ws = (char*)d_ws;
  __hip_bfloat16* wsLN1 = (__hip_bfloat16*)(ws);
  __hip_bfloat16* wsPRJ = (__hip_bfloat16*)(ws);
  __hip_bfloat16* wsPINC= (__hip_bfloat16*)(ws);                  // 16896*1024*2 = 34,603,008
  __hip_bfloat16* wsLN2C= (__hip_bfloat16*)(ws + 34603008UL);     // 16896*192*2  =  6,488,064
  __hip_bfloat16* wsATT = (__hip_bfloat16*)(ws + 50331648UL);
  __hip_bfloat16* wsX2  = (__hip_bfloat16*)(ws + 50331648UL);
  float*          wsST  = (float*)         (ws + 100663296UL);
  __hip_bfloat16* wsQKV = (__hip_bfloat16*)(ws + 101711872UL);
  __hip_bfloat16* wsGT  = (__hip_bfloat16*)(ws + 101711872UL);    // 16384*512*2 = 16,777,216
  __hip_bfloat16* wsWA  = (__hip_bfloat16*)(ws + 118489088UL);    // 9*512*2 = 9,216 B
  __hip_bfloat16* wsWG  = (__hip_bfloat16*)(ws + 118507520UL);    // 9,216 B (< 120,586,240)
  __hip_bfloat16* wsPW  = (__hip_bfloat16*)(ws + 120586240UL);    // 192*512
  __hip_bfloat16* wsQW  = (__hip_bfloat16*)(ws + 120782848UL);    // 110592
  __hip_bfloat16* wsPJW = (__hip_bfloat16*)(ws + 121004032UL);    // 36864
  __hip_bfloat16* wsPIW = (__hip_bfloat16*)(ws + 121077760UL);    // 1024*192 = 196608
  float* out = (float*)d_out;

  // weight conversion / padding
  kcvt<<<(110592 + 255) / 256, 256, 0, stream>>>(qkv_w, wsQW, 110592);
  kcvt<<<(36864 + 255) / 256, 256, 0, stream>>>(proj_w, wsPJW, 36864);
  k0_padpout<<<384, 256, 0, stream>>>(pout_w, wsPW);
  k0_padpin<<<768, 256, 0, stream>>>(pin_w, wsPIW);
  // LN1 + shift + window partition -> wsLN1 (window token-major, 192)
  k1_ln_window<<<32768, 256, 0, stream>>>(x, norm1_w, norm1_b, wsLN1);
  // qkv GEMM + attention, 8 chunks of 256 windows (16384 tokens)
  for (int c = 0; c < 8; ++c) {
    gemm_lds<4, 2, 0><<<dim3(9, 128), 256, 0, stream>>>(
        wsLN1 + (long)c * 16384 * CDIM, wsQW, nullptr, wsQKV, 192, 192, 192, 576);
    k3_attn<<<dim3(8, 256), 64, 0, stream>>>(wsQKV, rpb, wsATT, c * 256);
  }
  // proj GEMM (+bias): window order -> wsPRJ
  gemm_lds<4, 2, 1><<<dim3(3, 1024), 256, 0, stream>>>(
      wsATT, wsPJW, proj_b, wsPRJ, 192, 192, 192, 192);
  // residual + unshift + LN2 stats -> wsX2 (token-major), wsST
  k4_resln<<<32768, 256, 0, stream>>>(x, wsPRJ, wsX2, wsST);
  // dw-weight transposed bf16 tables (region free after attention phase)
  k0_wtap<<<18, 256, 0, stream>>>(dw_w, wsWA, wsWG);
  // FFN, 8 chunks of 64 image rows (per batch), 1-row halo
  for (int cc = 0; cc < 8; ++cc) {
    int b = cc >> 2, r0 = (cc & 3) * 64;
    k5_ln2<<<1584, 256, 0, stream>>>(wsX2, wsST, norm2_w, norm2_b, wsLN2C, b, r0);
    gemm_lds<4, 2, 0><<<dim3(16, 132), 256, 0, stream>>>(
        wsLN2C, wsPIW, nullptr, wsPINC, 192, 192, 192, 1024);
    k7_dwgate<<<4096, 256, 0, stream>>>(wsPINC, wsWA, wsWG, wsGT, r0);
    gemm_pout<<<dim3(128, 3), 256, 0, stream>>>(wsPW, wsGT, wsX2, out, b, r0);
  }
}